// Round 3
// baseline (5548.432 us; speedup 1.0000x reference)
//
#include <hip/hip_runtime.h>

namespace {
constexpr int N_PTS = 50000;
constexpr int KNB   = 6;
constexpr int PROW  = 7;        // K+1 rows per point
constexpr int VOUT  = 4;
constexpr int DPOS  = 32, DGEO = 128, DPARAM = 32;
constexpr int DCTX  = DPOS + DGEO + DPARAM;   // 192
constexpr int H1    = 256, H2 = 128;
constexpr int WAVES = 4;                      // waves per block
constexpr int PPW   = 2;                      // points per wave
constexpr int RPW   = PROW * PPW;             // 14 rows per wave
constexpr int PPB   = WAVES * PPW;            // 8 points per block
}

__device__ __forceinline__ float4 ld4(const float* p) {
  return *reinterpret_cast<const float4*>(p);
}

#define FMA4(acc, s, wv) do { \
  (acc).x = fmaf((s), (wv).x, (acc).x); \
  (acc).y = fmaf((s), (wv).y, (acc).y); \
  (acc).z = fmaf((s), (wv).z, (acc).z); \
  (acc).w = fmaf((s), (wv).w, (acc).w); } while (0)

// Block: 4 waves x 2 points. Each wave computes 14 rows x 256 cols per layer,
// weight float4 shared across 14 rows in registers (2x the FLOP/byte of
// 1-pt/wave). Per-layer __syncthreads keeps the 4 waves streaming the same
// weight lines (L1 temporal reuse, L2 traffic /4). Activations live in a
// single in-place LDS buffer (safe: all acc finalized before any store).
extern "C" __global__ void __launch_bounds__(256, 2)
surf_calc_kernel(const float* __restrict__ centers,
                 const float* __restrict__ enc_g,
                 const float* __restrict__ enc_node,
                 const float* __restrict__ nbrs,
                 const float* __restrict__ normals,
                 const float* __restrict__ nbr_normals,
                 const float* __restrict__ areas,
                 const float* __restrict__ nbr_areas,
                 const float* __restrict__ gpv,
                 const float* __restrict__ gpr,
                 const float* __restrict__ pW,
                 const float* __restrict__ pb,
                 const float* __restrict__ bW1,
                 const float* __restrict__ bb1,
                 const float* __restrict__ bW2,
                 const float* __restrict__ bb2,
                 const float* __restrict__ aW1,
                 const float* __restrict__ ab1,
                 const float* __restrict__ aW2,
                 const float* __restrict__ ab2,
                 const float* __restrict__ aW3,
                 const float* __restrict__ ab3,
                 float* __restrict__ out) {
  __shared__ float sA[WAVES][RPW][H1];   // 57344 B, in-place activations
  __shared__ float sCtx[PPB][DCTX];      // 6144 B
  __shared__ float sVol[PPB][PROW][8];   // 1792 B
  __shared__ float sInvd[PPB][8];        // 256 B   -> total exactly 64 KiB

  const int w    = threadIdx.x >> 6;
  const int lane = threadIdx.x & 63;
  const int p0g  = blockIdx.x * PPB + w * PPW;  // wave's first point
  const int c4   = lane * 4;
  const int c2   = lane * 2;

  // ---------------- prologue: ctx, vol rows, inv_dist ----------------
#pragma unroll
  for (int pt = 0; pt < PPW; pt++) {
    const int n = p0g + pt;
    const int s = w * PPW + pt;
    for (int idx = lane; idx < DPOS + DGEO; idx += 64) {
      float vv = (idx < DPOS) ? enc_node[n * DPOS + idx]
                              : enc_g[n * DGEO + (idx - DPOS)];
      sCtx[s][idx] = vv;
    }
    if (lane < DPARAM) {
      float q0 = gpv[0] / gpr[0];
      float q1 = gpv[1] / gpr[1];
      float pe = fmaf(q0, pW[lane], fmaf(q1, pW[DPARAM + lane], pb[lane]));
      sCtx[s][DPOS + DGEO + lane] = fmaxf(pe, 0.0f);
    }
  }
  if (lane < RPW) {
    const int pt = lane / PROW;
    const int r  = lane % PROW;
    const int n  = p0g + pt;
    const int s  = w * PPW + pt;
    float rr[7];
    if (r == 0) {
      rr[0] = centers[n * 3 + 0]; rr[1] = centers[n * 3 + 1]; rr[2] = centers[n * 3 + 2];
      rr[3] = normals[n * 3 + 0]; rr[4] = normals[n * 3 + 1]; rr[5] = normals[n * 3 + 2];
      rr[6] = logf(areas[n]) * 0.1f;
    } else {
      const int k   = r - 1;
      const int b3i = (n * KNB + k) * 3;
      rr[0] = nbrs[b3i + 0] + 1e-6f;
      rr[1] = nbrs[b3i + 1] + 1e-6f;
      rr[2] = nbrs[b3i + 2] + 1e-6f;
      rr[3] = nbr_normals[b3i + 0] + 1e-6f;
      rr[4] = nbr_normals[b3i + 1] + 1e-6f;
      rr[5] = nbr_normals[b3i + 2] + 1e-6f;
      rr[6] = logf(nbr_areas[n * KNB + k]) * 0.1f + 1e-6f;
    }
#pragma unroll
    for (int j = 0; j < 7; j++) sVol[s][r][j] = rr[j];
  }
  __syncthreads();
  if (lane < PPW * KNB) {   // 12 lanes: 2 pts x 6 neighbors
    const int pt = lane / KNB;
    const int k  = lane % KNB;
    const int s  = w * PPW + pt;
    float acc = 0.0f;
#pragma unroll
    for (int j = 0; j < 7; j++) {
      float d = sVol[s][0][j] - sVol[s][k + 1][j];
      acc = fmaf(d, d, acc);
    }
    sInvd[s][k] = 1.0f / sqrtf(acc);
  }
  __syncthreads();

  // ---------------- per-variable MLP chain ----------------
  for (int v = 0; v < VOUT; v++) {
    // ---- L1: h = relu(vol @ bW1 + bb1) -> sA ----
    {
      const float* Wp = bW1 + v * PROW * H1 + c4;
      float4 bv = ld4(bb1 + v * H1 + c4);
      float4 acc[RPW];
#pragma unroll
      for (int p = 0; p < RPW; p++) acc[p] = bv;
#pragma unroll
      for (int j = 0; j < 7; j++) {
        float4 wv = ld4(Wp + j * H1);
#pragma unroll
        for (int p = 0; p < RPW; p++) {
          float a = sVol[w * PPW + p / PROW][p % PROW][j];
          FMA4(acc[p], a, wv);
        }
      }
#pragma unroll
      for (int p = 0; p < RPW; p++) {
        float4 r;
        r.x = fmaxf(acc[p].x, 0.f); r.y = fmaxf(acc[p].y, 0.f);
        r.z = fmaxf(acc[p].z, 0.f); r.w = fmaxf(acc[p].w, 0.f);
        *reinterpret_cast<float4*>(&sA[w][p][c4]) = r;
      }
    }
    __syncthreads();

    // ---- L2: basis = relu(h @ bW2 + bb2), in place ----
    {
      const float* Wp = bW2 + v * H1 * H1 + c4;
      float4 bv = ld4(bb2 + v * H1 + c4);
      float4 acc[RPW];
#pragma unroll
      for (int p = 0; p < RPW; p++) acc[p] = bv;
#pragma unroll 2
      for (int k = 0; k < H1; k += 4) {
        float4 w0 = ld4(Wp);
        float4 w1 = ld4(Wp + H1);
        float4 w2 = ld4(Wp + 2 * H1);
        float4 w3 = ld4(Wp + 3 * H1);
        Wp += 4 * H1;
#pragma unroll
        for (int p = 0; p < RPW; p++) {
          float4 a = ld4(&sA[w][p][k]);
          FMA4(acc[p], a.x, w0);
          FMA4(acc[p], a.y, w1);
          FMA4(acc[p], a.z, w2);
          FMA4(acc[p], a.w, w3);
        }
      }
#pragma unroll
      for (int p = 0; p < RPW; p++) {
        float4 r;
        r.x = fmaxf(acc[p].x, 0.f); r.y = fmaxf(acc[p].y, 0.f);
        r.z = fmaxf(acc[p].z, 0.f); r.w = fmaxf(acc[p].w, 0.f);
        *reinterpret_cast<float4*>(&sA[w][p][c4]) = r;
      }
    }
    __syncthreads();

    // ---- agg1: a1 = relu([basis|ctx] @ aW1 + ab1), in place ----
    {
      // ctx part: one row per point (broadcast across the 7 P-rows)
      const float* Wc = aW1 + v * 448 * H1 + H1 * H1 + c4;   // rows 256..447
      float4 cp0 = ld4(ab1 + v * H1 + c4);
      float4 cp1 = cp0;
#pragma unroll 2
      for (int k = 0; k < DCTX; k += 4) {
        float4 w0 = ld4(Wc);
        float4 w1 = ld4(Wc + H1);
        float4 w2 = ld4(Wc + 2 * H1);
        float4 w3 = ld4(Wc + 3 * H1);
        Wc += 4 * H1;
        float4 a0 = ld4(&sCtx[w * PPW + 0][k]);
        float4 a1 = ld4(&sCtx[w * PPW + 1][k]);
        FMA4(cp0, a0.x, w0); FMA4(cp1, a1.x, w0);
        FMA4(cp0, a0.y, w1); FMA4(cp1, a1.y, w1);
        FMA4(cp0, a0.z, w2); FMA4(cp1, a1.z, w2);
        FMA4(cp0, a0.w, w3); FMA4(cp1, a1.w, w3);
      }
      float4 acc[RPW];
#pragma unroll
      for (int p = 0; p < RPW; p++) acc[p] = (p < PROW) ? cp0 : cp1;
      const float* Wp = aW1 + v * 448 * H1 + c4;             // rows 0..255
#pragma unroll 2
      for (int k = 0; k < H1; k += 4) {
        float4 w0 = ld4(Wp);
        float4 w1 = ld4(Wp + H1);
        float4 w2 = ld4(Wp + 2 * H1);
        float4 w3 = ld4(Wp + 3 * H1);
        Wp += 4 * H1;
#pragma unroll
        for (int p = 0; p < RPW; p++) {
          float4 a = ld4(&sA[w][p][k]);
          FMA4(acc[p], a.x, w0);
          FMA4(acc[p], a.y, w1);
          FMA4(acc[p], a.z, w2);
          FMA4(acc[p], a.w, w3);
        }
      }
#pragma unroll
      for (int p = 0; p < RPW; p++) {
        float4 r;
        r.x = fmaxf(acc[p].x, 0.f); r.y = fmaxf(acc[p].y, 0.f);
        r.z = fmaxf(acc[p].z, 0.f); r.w = fmaxf(acc[p].w, 0.f);
        *reinterpret_cast<float4*>(&sA[w][p][c4]) = r;
      }
    }
    __syncthreads();

    // ---- agg2 (256->128) + agg3 (128->1) + combine ----
    {
      const float* Wp = aW2 + v * H1 * H2 + c2;
      float2 acc2[RPW];
      float2 bv = *reinterpret_cast<const float2*>(ab2 + v * H2 + c2);
#pragma unroll
      for (int p = 0; p < RPW; p++) acc2[p] = bv;
#pragma unroll 2
      for (int k = 0; k < H1; k += 4) {
        float2 w0 = *reinterpret_cast<const float2*>(Wp);
        float2 w1 = *reinterpret_cast<const float2*>(Wp + H2);
        float2 w2 = *reinterpret_cast<const float2*>(Wp + 2 * H2);
        float2 w3 = *reinterpret_cast<const float2*>(Wp + 3 * H2);
        Wp += 4 * H2;
#pragma unroll
        for (int p = 0; p < RPW; p++) {
          float4 a = ld4(&sA[w][p][k]);
          acc2[p].x = fmaf(a.x, w0.x, acc2[p].x); acc2[p].y = fmaf(a.x, w0.y, acc2[p].y);
          acc2[p].x = fmaf(a.y, w1.x, acc2[p].x); acc2[p].y = fmaf(a.y, w1.y, acc2[p].y);
          acc2[p].x = fmaf(a.z, w2.x, acc2[p].x); acc2[p].y = fmaf(a.z, w2.y, acc2[p].y);
          acc2[p].x = fmaf(a.w, w3.x, acc2[p].x); acc2[p].y = fmaf(a.w, w3.y, acc2[p].y);
        }
      }
      const float w3a = aW3[v * H2 + c2];
      const float w3b = aW3[v * H2 + c2 + 1];
      float part[RPW];
#pragma unroll
      for (int p = 0; p < RPW; p++) {
        float x = fmaxf(acc2[p].x, 0.f);
        float y = fmaxf(acc2[p].y, 0.f);
        part[p] = fmaf(x, w3a, y * w3b);
      }
#pragma unroll
      for (int p = 0; p < RPW; p++) {
        float s = part[p];
#pragma unroll
        for (int m = 32; m > 0; m >>= 1) s += __shfl_xor(s, m, 64);
        part[p] = s;
      }
      if (lane == 0) {
        const float b3 = ab3[v];
#pragma unroll
        for (int pt = 0; pt < PPW; pt++) {
          const int s = w * PPW + pt;
          float o0 = part[pt * PROW] + b3;
          float on = 0.f, ds = 0.f;
#pragma unroll
          for (int k = 0; k < KNB; k++) {
            float id = sInvd[s][k];
            on = fmaf(part[pt * PROW + 1 + k] + b3, id, on);
            ds += id;
          }
          out[(p0g + pt) * VOUT + v] = 0.5f * o0 + 0.5f * on / ds;
        }
      }
    }
    __syncthreads();
  }
}

extern "C" void kernel_launch(void* const* d_in, const int* in_sizes, int n_in,
                              void* d_out, int out_size, void* d_ws, size_t ws_size,
                              hipStream_t stream) {
  const float* centers     = (const float*)d_in[0];
  const float* enc_g       = (const float*)d_in[1];
  const float* enc_node    = (const float*)d_in[2];
  const float* nbrs        = (const float*)d_in[3];
  const float* normals     = (const float*)d_in[4];
  const float* nbr_normals = (const float*)d_in[5];
  const float* areas       = (const float*)d_in[6];
  const float* nbr_areas   = (const float*)d_in[7];
  const float* gpv         = (const float*)d_in[8];
  const float* gpr         = (const float*)d_in[9];
  const float* pW          = (const float*)d_in[10];
  const float* pb          = (const float*)d_in[11];
  const float* bW1         = (const float*)d_in[12];
  const float* bb1         = (const float*)d_in[13];
  const float* bW2         = (const float*)d_in[14];
  const float* bb2         = (const float*)d_in[15];
  const float* aW1         = (const float*)d_in[16];
  const float* ab1         = (const float*)d_in[17];
  const float* aW2         = (const float*)d_in[18];
  const float* ab2         = (const float*)d_in[19];
  const float* aW3         = (const float*)d_in[20];
  const float* ab3         = (const float*)d_in[21];
  float* out = (float*)d_out;

  surf_calc_kernel<<<dim3(N_PTS / PPB), dim3(256), 0, stream>>>(
      centers, enc_g, enc_node, nbrs, normals, nbr_normals, areas, nbr_areas,
      gpv, gpr, pW, pb, bW1, bb1, bW2, bb2, aW1, ab1, aW2, ab2, aW3, ab3, out);
}

// Round 4
// 744.762 us; speedup vs baseline: 7.4499x; 7.4499x over previous
//
#include <hip/hip_runtime.h>

typedef __attribute__((ext_vector_type(8))) _Float16 f16x8;
typedef __attribute__((ext_vector_type(4))) float f32x4;

namespace {
constexpr int N_PTS = 50000;
constexpr int VOUT  = 4;
constexpr int PPB   = 9;     // points per block
constexpr int MROWS = 64;    // 63 real rows + 1 pad
constexpr int ABYTES = 896;  // A row stride: 448 f16

// packed-weight region offsets in d_ws (f16 elements)
constexpr int OFF_BW1 = 0;        // V * (Kg=4)  * 256 * 8   (K 7 padded to 32)
constexpr int OFF_BW2 = 32768;    // V * (Kg=32) * 256 * 8
constexpr int OFF_AW1 = 294912;   // V * (Kg=56) * 256 * 8   (K=448)
constexpr int OFF_AW2 = 753664;   // V * (Kg=32) * 128 * 8
constexpr int PACK_TOTAL = 884736;
}

// ---- prep: fp32 weights -> f16, packed so lane's 8 k-elems are contiguous:
// Bp[g][n][j] with k = g*8+j, flat = (g*N + n)*8 + j  (zero-pad k >= Ksrc)
__global__ __launch_bounds__(256) void pack_weights_kernel(
    const float* __restrict__ bW1, const float* __restrict__ bW2,
    const float* __restrict__ aW1, const float* __restrict__ aW2,
    _Float16* __restrict__ out) {
  int t = blockIdx.x * 256 + threadIdx.x;
  const float* W; int Kg, N, Ksrc, base;
  if (t < OFF_BW2)      { base = OFF_BW1; Kg = 4;  N = 256; Ksrc = 7;   W = bW1; }
  else if (t < OFF_AW1) { base = OFF_BW2; Kg = 32; N = 256; Ksrc = 256; W = bW2; }
  else if (t < OFF_AW2) { base = OFF_AW1; Kg = 56; N = 256; Ksrc = 448; W = aW1; }
  else                  { base = OFF_AW2; Kg = 32; N = 128; Ksrc = 256; W = aW2; }
  int local = t - base;
  int vsz = Kg * N * 8;
  int v = local / vsz;
  int rem = local - v * vsz;
  int g  = rem / (N * 8);
  int r2 = rem - g * (N * 8);
  int n = r2 >> 3;
  int j = r2 & 7;
  int k = g * 8 + j;
  float val = (k < Ksrc) ? W[(v * Ksrc + k) * N + n] : 0.0f;
  out[t] = (_Float16)val;
}

// A-frag: lane l, elem j <-> A[16*mt + (l&15)][kb*32 + (l>>4)*8 + j]
// B-frag: lane l, elem j <-> B[kb*32 + (l>>4)*8 + j][n0 + 16*nt + (l&15)]
// C/D:    lane l, reg  r <-> C[16*mt + (l>>4)*4 + r][n0 + 16*nt + (l&15)]
template<int NT>
__device__ __forceinline__ void run_gemm(
    const _Float16* __restrict__ Bp, int Nn, int KB,
    const char* __restrict__ Ab, int abytes, int aswz,
    int lane, int n0, f32x4 acc[4][NT]) {
  const int q = lane >> 4, c = lane & 15;
  const char* Bb = (const char*)Bp;
  f16x8 bcur[NT], bnext[NT];
#pragma unroll
  for (int nt = 0; nt < NT; nt++)
    bcur[nt] = *(const f16x8*)(Bb + ((q * Nn + n0 + 16 * nt + c) << 4));
  for (int kb = 0; kb < KB; kb++) {
    f16x8 a[4];
    const int koff = (kb * 64 + q * 16) ^ aswz;
#pragma unroll
    for (int mt = 0; mt < 4; mt++)
      a[mt] = *(const f16x8*)(Ab + (16 * mt + c) * abytes + koff);
    if (kb + 1 < KB) {
#pragma unroll
      for (int nt = 0; nt < NT; nt++)
        bnext[nt] = *(const f16x8*)(Bb + ((((kb + 1) * 4 + q) * Nn + n0 + 16 * nt + c) << 4));
    }
#pragma unroll
    for (int mt = 0; mt < 4; mt++)
#pragma unroll
      for (int nt = 0; nt < NT; nt++)
        acc[mt][nt] = __builtin_amdgcn_mfma_f32_16x16x32_f16(a[mt], bcur[nt], acc[mt][nt], 0, 0, 0);
    if (kb + 1 < KB) {
#pragma unroll
      for (int nt = 0; nt < NT; nt++) bcur[nt] = bnext[nt];
    }
  }
}

template<int NT>
__device__ __forceinline__ void epilogue_relu(
    f32x4 acc[4][NT], const float* __restrict__ bias,
    int lane, int n0, char* __restrict__ Ab) {
  const int q = lane >> 4, c = lane & 15;
#pragma unroll
  for (int nt = 0; nt < NT; nt++) {
    const int col = n0 + 16 * nt + c;
    const float bv = bias[col];
#pragma unroll
    for (int mt = 0; mt < 4; mt++) {
#pragma unroll
      for (int r = 0; r < 4; r++) {
        const int row = 16 * mt + 4 * q + r;
        float y = fmaxf(acc[mt][nt][r] + bv, 0.0f);
        *(_Float16*)(Ab + row * ABYTES + ((2 * col) ^ (((4 * q + r) & 7) << 4))) = (_Float16)y;
      }
    }
  }
}

__global__ __launch_bounds__(256, 2) void surf_mfma_kernel(
    const float* __restrict__ centers, const float* __restrict__ enc_g,
    const float* __restrict__ enc_node, const float* __restrict__ nbrs,
    const float* __restrict__ normals, const float* __restrict__ nbr_normals,
    const float* __restrict__ areas, const float* __restrict__ nbr_areas,
    const float* __restrict__ gpv, const float* __restrict__ gpr,
    const float* __restrict__ pW, const float* __restrict__ pb,
    const float* __restrict__ bb1, const float* __restrict__ bb2,
    const float* __restrict__ ab1, const float* __restrict__ ab2,
    const float* __restrict__ aW3, const float* __restrict__ ab3,
    const _Float16* __restrict__ Wp, float* __restrict__ out) {
  __shared__ _Float16 sA[MROWS * 448];   // [row][448] f16, XOR-swizzled cols
  __shared__ _Float16 sVol[MROWS * 40];  // [row][40] f16 (cols 7..31 zero, pad)
  __shared__ float sVolF[63][7];
  __shared__ float sPE[32];
  __shared__ float sW3[128];
  __shared__ float sPart[4][64];
  __shared__ float sRow[64];
  __shared__ float sInvd[54];

  const int t    = threadIdx.x;
  const int lane = t & 63;
  const int w    = t >> 6;
  const int blk  = blockIdx.x;
  char* Ab = (char*)sA;

  // ---- prologue phase 1: param_enc + vol rows (f32 + f16) ----
  if (t < 32) {
    float q0 = gpv[0] / gpr[0], q1 = gpv[1] / gpr[1];
    sPE[t] = fmaxf(fmaf(q0, pW[t], fmaf(q1, pW[32 + t], pb[t])), 0.0f);
  }
  if (t < 64) {
    float f[7];
    if (t < 63) {
      int pt = t / 7, p = t - pt * 7;
      int n = min(blk * PPB + pt, N_PTS - 1);
      if (p == 0) {
        f[0] = centers[n * 3];     f[1] = centers[n * 3 + 1]; f[2] = centers[n * 3 + 2];
        f[3] = normals[n * 3];     f[4] = normals[n * 3 + 1]; f[5] = normals[n * 3 + 2];
        f[6] = logf(areas[n]) * 0.1f;
      } else {
        int k = p - 1;
        int b3i = (n * 6 + k) * 3;
        f[0] = nbrs[b3i] + 1e-6f;        f[1] = nbrs[b3i + 1] + 1e-6f;
        f[2] = nbrs[b3i + 2] + 1e-6f;    f[3] = nbr_normals[b3i] + 1e-6f;
        f[4] = nbr_normals[b3i + 1] + 1e-6f; f[5] = nbr_normals[b3i + 2] + 1e-6f;
        f[6] = logf(nbr_areas[n * 6 + k]) * 0.1f + 1e-6f;
      }
#pragma unroll
      for (int j = 0; j < 7; j++) sVolF[t][j] = f[j];
    } else {
#pragma unroll
      for (int j = 0; j < 7; j++) f[j] = 0.0f;
    }
#pragma unroll
    for (int j = 0; j < 7; j++) sVol[t * 40 + j] = (_Float16)f[j];
#pragma unroll
    for (int j = 7; j < 40; j++) sVol[t * 40 + j] = (_Float16)0.0f;
  }
  __syncthreads();

  // ---- prologue phase 2: inv_dist + ctx (A cols 256..448) ----
  if (t < 54) {
    int pt = t / 6, k = t - pt * 6;
    float ss = 0.0f;
#pragma unroll
    for (int j = 0; j < 7; j++) {
      float d = sVolF[pt * 7][j] - sVolF[pt * 7 + 1 + k][j];
      ss = fmaf(d, d, ss);
    }
    sInvd[t] = 1.0f / sqrtf(ss);
  }
  for (int idx = t; idx < 63 * 192; idx += 256) {
    int row = idx / 192, j = idx - row * 192;
    int n = min(blk * PPB + row / 7, N_PTS - 1);
    float val = (j < 32) ? enc_node[n * 32 + j]
              : (j < 160) ? enc_g[n * 128 + (j - 32)]
              : sPE[j - 160];
    *(_Float16*)(Ab + row * ABYTES + ((2 * (256 + j)) ^ ((row & 7) << 4))) = (_Float16)val;
  }
  __syncthreads();

  const int aswz = (lane & 7) << 4;
  const int n0w  = 64 * w;

  for (int v = 0; v < VOUT; v++) {
    // ---- L1: vol(7, pad 32) @ bW1 -> sA[:, 0:256] ----
    {
      f32x4 acc[4][4] = {};
      run_gemm<4>(Wp + OFF_BW1 + v * 8192, 256, 1, (const char*)sVol, 80, 0, lane, n0w, acc);
      // reads sVol only; prior readers of sA[0:256] finished >=2 barriers ago
      epilogue_relu<4>(acc, bb1 + v * 256, lane, n0w, Ab);
    }
    __syncthreads();
    // ---- L2: sA[0:256] @ bW2 -> sA[0:256] (in place) ----
    {
      f32x4 acc[4][4] = {};
      run_gemm<4>(Wp + OFF_BW2 + v * 65536, 256, 8, Ab, ABYTES, aswz, lane, n0w, acc);
      __syncthreads();
      epilogue_relu<4>(acc, bb2 + v * 256, lane, n0w, Ab);
    }
    __syncthreads();
    // ---- agg1: sA[0:448] @ aW1 -> sA[0:256] ----
    {
      f32x4 acc[4][4] = {};
      run_gemm<4>(Wp + OFF_AW1 + v * 114688, 256, 14, Ab, ABYTES, aswz, lane, n0w, acc);
      __syncthreads();
      epilogue_relu<4>(acc, ab1 + v * 256, lane, n0w, Ab);
    }
    __syncthreads();
    // ---- agg2: sA[0:256] @ aW2 -> sA[0:128] ----
    {
      f32x4 acc[4][2] = {};
      run_gemm<2>(Wp + OFF_AW2 + v * 32768, 128, 8, Ab, ABYTES, aswz, lane, 32 * w, acc);
      __syncthreads();
      epilogue_relu<2>(acc, ab2 + v * 128, lane, 32 * w, Ab);
      if (t < 128) sW3[t] = aW3[v * 128 + t];
    }
    __syncthreads();
    // ---- agg3: per-row dot(128) in fp32, 4-way split across waves ----
    {
      int row = t & 63, h = t >> 6;
      float s = 0.0f;
      int swzm = (row & 7) << 4;
#pragma unroll
      for (int cc = 0; cc < 4; cc++) {
        int k0 = h * 32 + cc * 8;
        f16x8 av = *(const f16x8*)(Ab + row * ABYTES + ((2 * k0) ^ swzm));
#pragma unroll
        for (int j = 0; j < 8; j++) s = fmaf((float)av[j], sW3[k0 + j], s);
      }
      sPart[h][row] = s;
    }
    __syncthreads();
    if (t < 64) sRow[t] = sPart[0][t] + sPart[1][t] + sPart[2][t] + sPart[3][t] + ab3[v];
    __syncthreads();
    if (t < PPB) {
      int n = blk * PPB + t;
      if (n < N_PTS) {
        float o0 = sRow[t * 7];
        float on = 0.0f, ds = 0.0f;
#pragma unroll
        for (int k = 0; k < 6; k++) {
          float id = sInvd[t * 6 + k];
          on = fmaf(sRow[t * 7 + 1 + k], id, on);
          ds += id;
        }
        out[n * VOUT + v] = 0.5f * o0 + 0.5f * on / ds;
      }
    }
    __syncthreads();
  }
}

extern "C" void kernel_launch(void* const* d_in, const int* in_sizes, int n_in,
                              void* d_out, int out_size, void* d_ws, size_t ws_size,
                              hipStream_t stream) {
  const float* centers     = (const float*)d_in[0];
  const float* enc_g       = (const float*)d_in[1];
  const float* enc_node    = (const float*)d_in[2];
  const float* nbrs        = (const float*)d_in[3];
  const float* normals     = (const float*)d_in[4];
  const float* nbr_normals = (const float*)d_in[5];
  const float* areas       = (const float*)d_in[6];
  const float* nbr_areas   = (const float*)d_in[7];
  const float* gpv         = (const float*)d_in[8];
  const float* gpr         = (const float*)d_in[9];
  const float* pW          = (const float*)d_in[10];
  const float* pb          = (const float*)d_in[11];
  const float* bW1         = (const float*)d_in[12];
  const float* bb1         = (const float*)d_in[13];
  const float* bW2         = (const float*)d_in[14];
  const float* bb2         = (const float*)d_in[15];
  const float* aW1         = (const float*)d_in[16];
  const float* ab1         = (const float*)d_in[17];
  const float* aW2         = (const float*)d_in[18];
  const float* ab2         = (const float*)d_in[19];
  const float* aW3         = (const float*)d_in[20];
  const float* ab3         = (const float*)d_in[21];
  float* out = (float*)d_out;
  _Float16* Wp = (_Float16*)d_ws;   // 1.77 MB packed f16 weights

  pack_weights_kernel<<<dim3(PACK_TOTAL / 256), dim3(256), 0, stream>>>(
      bW1, bW2, aW1, aW2, Wp);

  const int nblocks = (N_PTS + PPB - 1) / PPB;  // 5556
  surf_mfma_kernel<<<dim3(nblocks), dim3(256), 0, stream>>>(
      centers, enc_g, enc_node, nbrs, normals, nbr_normals, areas, nbr_areas,
      gpv, gpr, pW, pb, bb1, bb2, ab1, ab2, aW3, ab3, Wp, out);
}